// Round 1
// baseline (1433.056 us; speedup 1.0000x reference)
//
#include <hip/hip_runtime.h>
#include <hip/hip_bf16.h>
#include <stdint.h>

typedef __attribute__((ext_vector_type(8))) short short8_t;   // 8 bf16
typedef __attribute__((ext_vector_type(4))) float f32x4;
typedef __attribute__((ext_vector_type(4))) int   i32x4;

#define AS1 __attribute__((address_space(1)))
#define AS3 __attribute__((address_space(3)))

__device__ __forceinline__ void gload_lds16(const void* g, void* l) {
    __builtin_amdgcn_global_load_lds((const AS1 unsigned int*)g,
                                     (AS3 unsigned int*)l, 16, 0, 0);
}

__device__ __forceinline__ unsigned short f2bf(float f) {
    unsigned int u = __float_as_uint(f);
    unsigned int r = (u + 0x7FFFu + ((u >> 16) & 1u)) >> 16;  // RNE
    return (unsigned short)r;
}
__device__ __forceinline__ float bf2f(unsigned short s) {
    return __uint_as_float(((unsigned int)s) << 16);
}

// ---------------- cast h (f32 -> bf16), 4 elems/thread ----------------
__global__ void cast_h_kernel(const float* __restrict__ h,
                              unsigned short* __restrict__ hb, int total4) {
    int t = blockIdx.x * blockDim.x + threadIdx.x;
    if (t >= total4) return;
    float4 v = ((const float4*)h)[t];
    ushort4 o;
    o.x = f2bf(v.x); o.y = f2bf(v.y); o.z = f2bf(v.z); o.w = f2bf(v.w);
    *(ushort4*)(hb + (size_t)t * 4) = o;
}

// ---------------- W[r][i][o] -> Wt[r][o][i] bf16 ----------------
__global__ void wt_kernel(const float* __restrict__ w,
                          unsigned short* __restrict__ wt) {
    int r = blockIdx.x;
    const float* wr = w + (size_t)r * 16384;
    unsigned short* wtr = wt + (size_t)r * 16384;
    for (int x = threadIdx.x; x < 16384; x += blockDim.x) {
        int i = x >> 7, o = x & 127;
        wtr[o * 128 + i] = f2bf(wr[x]);
    }
}

// ---------------- GEMM: hw[rloc] = h_bf @ W[r0+rloc]  (128x128 tile) ----------------
// LDS layout: row-major [128][128] bf16 with byte ^= ((row&7)<<4) XOR swizzle.
// Filled by global_load_lds (linear dest) with pre-swizzled global source.
__global__ __launch_bounds__(256, 2) void gemm_kernel(
    const unsigned short* __restrict__ hb,   // [NP][128] bf16
    const unsigned short* __restrict__ wt,   // [R][128][128] bf16 (Wt = W^T per rel)
    unsigned short* __restrict__ hw,         // [RC][NP][128] bf16
    int r0, int np)
{
    __shared__ __align__(16) char smem[65536];
    char* ldsA = smem;
    char* ldsB = smem + 32768;
    const int tid  = threadIdx.x;
    const int lane = tid & 63;
    const int w    = tid >> 6;
    const int rloc = blockIdx.y;
    const int rel  = r0 + rloc;
    const size_t rowBase = (size_t)blockIdx.x * 128;

    const char* gA = (const char*)(hb + rowBase * 128);
    const char* gB = (const char*)(wt + (size_t)rel * 16384);

    // stage A and B: 8 wave-iters x 1KB each; source pre-swizzled (involution XOR)
#pragma unroll
    for (int it = 0; it < 8; ++it) {
        int p = it * 4096 + w * 1024 + lane * 16;
        int row = p >> 8;
        int inrow = p & 255;
        int so = (row << 8) + (inrow ^ ((row & 7) << 4));
        gload_lds16(gA + so, ldsA + p);
        gload_lds16(gB + so, ldsB + p);
    }
    __syncthreads();

    const int wr = w >> 1, wc = w & 1;
    const int l15 = lane & 15, kb = lane >> 4;
    f32x4 acc[4][4];
#pragma unroll
    for (int m = 0; m < 4; ++m)
#pragma unroll
        for (int n = 0; n < 4; ++n) acc[m][n] = (f32x4){0.f, 0.f, 0.f, 0.f};

#pragma unroll
    for (int kk = 0; kk < 4; ++kk) {
        short8_t a[4], b[4];
#pragma unroll
        for (int m = 0; m < 4; ++m) {
            int row = wr * 64 + m * 16 + l15;
            int byte = row * 256 + ((kk * 64 + kb * 16) ^ ((row & 7) << 4));
            a[m] = *(const short8_t*)(ldsA + byte);
        }
#pragma unroll
        for (int n = 0; n < 4; ++n) {
            int row = wc * 64 + n * 16 + l15;
            int byte = row * 256 + ((kk * 64 + kb * 16) ^ ((row & 7) << 4));
            b[n] = *(const short8_t*)(ldsB + byte);
        }
#pragma unroll
        for (int m = 0; m < 4; ++m)
#pragma unroll
            for (int n = 0; n < 4; ++n)
                acc[m][n] = __builtin_amdgcn_mfma_f32_16x16x32_bf16(
                    a[m], b[n], acc[m][n], 0, 0, 0);
    }

    __syncthreads();
    // C -> LDS as bf16 (swizzled), then coalesced global store
#pragma unroll
    for (int m = 0; m < 4; ++m) {
#pragma unroll
        for (int n = 0; n < 4; ++n) {
            int col = wc * 64 + n * 16 + l15;
#pragma unroll
            for (int j = 0; j < 4; ++j) {
                int row = wr * 64 + m * 16 + kb * 4 + j;
                int byte = row * 256 + ((col * 2) ^ ((row & 7) << 4));
                *(unsigned short*)(smem + byte) = f2bf(acc[m][n][j]);
            }
        }
    }
    __syncthreads();

    char* gC = (char*)(hw + ((size_t)rloc * np + rowBase) * 128);
#pragma unroll
    for (int j = 0; j < 8; ++j) {
        int p = j * 4096 + tid * 16;       // consecutive lanes -> consecutive 16B
        int row = p >> 8;
        int inrow = p & 255;
        i32x4 v = *(const i32x4*)(smem + row * 256 + (inrow ^ ((row & 7) << 4)));
        *(i32x4*)(gC + p) = v;
    }
}

// ---------------- per-edge gather + atomic scatter ----------------
__global__ void scatter_kernel(const unsigned short* __restrict__ hw,
                               const int* __restrict__ rel,
                               const int* __restrict__ src,
                               const int* __restrict__ dst,
                               float* __restrict__ agg,
                               int r0, int rc, int nE, int np)
{
    int gw   = (blockIdx.x * blockDim.x + threadIdx.x) >> 6;
    int lane = threadIdx.x & 63;
    int nW   = (gridDim.x * blockDim.x) >> 6;
    for (int e = gw; e < nE; e += nW) {
        int r = rel[e] - r0;
        if ((unsigned)r >= (unsigned)rc) continue;
        int s = src[e];
        int d = dst[e];
        unsigned int v = *(const unsigned int*)(hw + ((size_t)r * np + s) * 128 + lane * 2);
        float f0 = bf2f((unsigned short)(v & 0xFFFFu));
        float f1 = bf2f((unsigned short)(v >> 16));
        float* ap = agg + (size_t)d * 128 + lane * 2;
        unsafeAtomicAdd(ap, f0);
        unsafeAtomicAdd(ap + 1, f1);
    }
}

// ---------------- out = relu(agg + bias) ----------------
__global__ void finalize_kernel(const float* __restrict__ agg,
                                const float* __restrict__ bias,
                                float* __restrict__ out, int total4) {
    int t = blockIdx.x * blockDim.x + threadIdx.x;
    if (t >= total4) return;
    float4 a = ((const float4*)agg)[t];
    float4 b = ((const float4*)bias)[t & 31];
    float4 o;
    o.x = fmaxf(a.x + b.x, 0.f);
    o.y = fmaxf(a.y + b.y, 0.f);
    o.z = fmaxf(a.z + b.z, 0.f);
    o.w = fmaxf(a.w + b.w, 0.f);
    ((float4*)out)[t] = o;
}

extern "C" void kernel_launch(void* const* d_in, const int* in_sizes, int n_in,
                              void* d_out, int out_size, void* d_ws, size_t ws_size,
                              hipStream_t stream) {
    const float* h    = (const float*)d_in[0];
    const float* w    = (const float*)d_in[1];
    const float* bias = (const float*)d_in[2];
    const int*   src  = (const int*)d_in[3];
    const int*   dst  = (const int*)d_in[4];
    const int*   rel  = (const int*)d_in[5];
    float* out = (float*)d_out;

    const int N  = in_sizes[0] / 128;
    const int E  = in_sizes[3];
    const int R  = in_sizes[1] / (128 * 128);
    const int NB = (N + 127) / 128;
    const int NP = NB * 128;

    char* ws = (char*)d_ws;
    size_t aggB = (size_t)N * 128 * 4;
    size_t hbB  = (size_t)NP * 128 * 2;
    size_t wtB  = (size_t)R * 128 * 128 * 2;
    float*          agg = (float*)ws;
    unsigned short* hb  = (unsigned short*)(ws + aggB);
    unsigned short* wt  = (unsigned short*)(ws + aggB + hbB);
    unsigned short* hw  = (unsigned short*)(ws + aggB + hbB + wtB);

    size_t perRel = (size_t)NP * 128 * 2;
    size_t fixed  = aggB + hbB + wtB;
    size_t avail  = ws_size > fixed ? ws_size - fixed : 0;
    int RC = (int)(avail / perRel);
    if (RC > R) RC = R;
    if (RC < 1) RC = 1;

    hipMemsetAsync(agg, 0, aggB, stream);
    if (NP > N)  // zero pad rows of h_bf16
        hipMemsetAsync(hb + (size_t)N * 128, 0, (size_t)(NP - N) * 128 * 2, stream);

    int total4 = N * 32;  // N*128/4
    cast_h_kernel<<<(total4 + 255) / 256, 256, 0, stream>>>(h, hb, total4);
    wt_kernel<<<R, 256, 0, stream>>>(w, wt);

    for (int r0 = 0; r0 < R; r0 += RC) {
        int rc = (R - r0 < RC) ? (R - r0) : RC;
        gemm_kernel<<<dim3(NB, rc), 256, 0, stream>>>(hb, wt, hw, r0, NP);
        scatter_kernel<<<2048, 256, 0, stream>>>(hw, rel, src, dst, agg, r0, rc, E, NP);
    }

    finalize_kernel<<<(total4 + 255) / 256, 256, 0, stream>>>(agg, bias, out, total4);
}

// Round 2
// 412.129 us; speedup vs baseline: 3.4772x; 3.4772x over previous
//
#include <hip/hip_runtime.h>
#include <hip/hip_bf16.h>
#include <stdint.h>

typedef __attribute__((ext_vector_type(8))) short short8_t;   // 8 bf16
typedef __attribute__((ext_vector_type(4))) float f32x4;
typedef __attribute__((ext_vector_type(4))) int   i32x4;

#define AS1 __attribute__((address_space(1)))
#define AS3 __attribute__((address_space(3)))

__device__ __forceinline__ void gload_lds16(const void* g, void* l) {
    __builtin_amdgcn_global_load_lds((const AS1 unsigned int*)g,
                                     (AS3 unsigned int*)l, 16, 0, 0);
}

__device__ __forceinline__ unsigned short f2bf(float f) {
    unsigned int u = __float_as_uint(f);
    unsigned int r = (u + 0x7FFFu + ((u >> 16) & 1u)) >> 16;  // RNE
    return (unsigned short)r;
}
__device__ __forceinline__ float bf2f(unsigned short s) {
    return __uint_as_float(((unsigned int)s) << 16);
}

// ---------------- cast h (f32 -> bf16), 4 elems/thread ----------------
__global__ void cast_h_kernel(const float* __restrict__ h,
                              unsigned short* __restrict__ hb, int total4) {
    int t = blockIdx.x * blockDim.x + threadIdx.x;
    if (t >= total4) return;
    float4 v = ((const float4*)h)[t];
    ushort4 o;
    o.x = f2bf(v.x); o.y = f2bf(v.y); o.z = f2bf(v.z); o.w = f2bf(v.w);
    *(ushort4*)(hb + (size_t)t * 4) = o;
}

// ---------------- W[r][i][o] -> Wt[r][o][i] bf16 ----------------
__global__ void wt_kernel(const float* __restrict__ w,
                          unsigned short* __restrict__ wt) {
    int r = blockIdx.x;
    const float* wr = w + (size_t)r * 16384;
    unsigned short* wtr = wt + (size_t)r * 16384;
    for (int x = threadIdx.x; x < 16384; x += blockDim.x) {
        int i = x >> 7, o = x & 127;
        wtr[o * 128 + i] = f2bf(wr[x]);
    }
}

// ---------------- GEMM: hw[rloc] = h_bf @ W[r0+rloc]  (128x128 tile) ----------------
__global__ __launch_bounds__(256, 2) void gemm_kernel(
    const unsigned short* __restrict__ hb,   // [NP][128] bf16
    const unsigned short* __restrict__ wt,   // [R][128][128] bf16 (Wt = W^T per rel)
    unsigned short* __restrict__ hw,         // [RC][NP][128] bf16
    int r0, int np)
{
    __shared__ __align__(16) char smem[65536];
    char* ldsA = smem;
    char* ldsB = smem + 32768;
    const int tid  = threadIdx.x;
    const int lane = tid & 63;
    const int w    = tid >> 6;
    const int rloc = blockIdx.y;
    const int rel  = r0 + rloc;
    const size_t rowBase = (size_t)blockIdx.x * 128;

    const char* gA = (const char*)(hb + rowBase * 128);
    const char* gB = (const char*)(wt + (size_t)rel * 16384);

#pragma unroll
    for (int it = 0; it < 8; ++it) {
        int p = it * 4096 + w * 1024 + lane * 16;
        int row = p >> 8;
        int inrow = p & 255;
        int so = (row << 8) + (inrow ^ ((row & 7) << 4));
        gload_lds16(gA + so, ldsA + p);
        gload_lds16(gB + so, ldsB + p);
    }
    __syncthreads();

    const int wr = w >> 1, wc = w & 1;
    const int l15 = lane & 15, kb = lane >> 4;
    f32x4 acc[4][4];
#pragma unroll
    for (int m = 0; m < 4; ++m)
#pragma unroll
        for (int n = 0; n < 4; ++n) acc[m][n] = (f32x4){0.f, 0.f, 0.f, 0.f};

#pragma unroll
    for (int kk = 0; kk < 4; ++kk) {
        short8_t a[4], b[4];
#pragma unroll
        for (int m = 0; m < 4; ++m) {
            int row = wr * 64 + m * 16 + l15;
            int byte = row * 256 + ((kk * 64 + kb * 16) ^ ((row & 7) << 4));
            a[m] = *(const short8_t*)(ldsA + byte);
        }
#pragma unroll
        for (int n = 0; n < 4; ++n) {
            int row = wc * 64 + n * 16 + l15;
            int byte = row * 256 + ((kk * 64 + kb * 16) ^ ((row & 7) << 4));
            b[n] = *(const short8_t*)(ldsB + byte);
        }
#pragma unroll
        for (int m = 0; m < 4; ++m)
#pragma unroll
            for (int n = 0; n < 4; ++n)
                acc[m][n] = __builtin_amdgcn_mfma_f32_16x16x32_bf16(
                    a[m], b[n], acc[m][n], 0, 0, 0);
    }

    __syncthreads();
#pragma unroll
    for (int m = 0; m < 4; ++m) {
#pragma unroll
        for (int n = 0; n < 4; ++n) {
            int col = wc * 64 + n * 16 + l15;
#pragma unroll
            for (int j = 0; j < 4; ++j) {
                int row = wr * 64 + m * 16 + kb * 4 + j;
                int byte = row * 256 + ((col * 2) ^ ((row & 7) << 4));
                *(unsigned short*)(smem + byte) = f2bf(acc[m][n][j]);
            }
        }
    }
    __syncthreads();

    char* gC = (char*)(hw + ((size_t)rloc * np + rowBase) * 128);
#pragma unroll
    for (int j = 0; j < 8; ++j) {
        int p = j * 4096 + tid * 16;
        int row = p >> 8;
        int inrow = p & 255;
        i32x4 v = *(const i32x4*)(smem + row * 256 + (inrow ^ ((row & 7) << 4)));
        *(i32x4*)(gC + p) = v;
    }
}

// ---------------- counting sort by dst ----------------
__global__ void count_kernel(const int* __restrict__ dst,
                             int* __restrict__ cnt, int nE) {
    int t = blockIdx.x * blockDim.x + threadIdx.x;
    int e = t * 4;
    if (e + 3 < nE) {
        int4 v = *(const int4*)(dst + e);
        atomicAdd(cnt + v.x, 1); atomicAdd(cnt + v.y, 1);
        atomicAdd(cnt + v.z, 1); atomicAdd(cnt + v.w, 1);
    } else {
        for (int j = 0; j < 4; ++j)
            if (e + j < nE) atomicAdd(cnt + dst[e + j], 1);
    }
}

#define SCAN_CHUNK 1024
__global__ void scan_partial(const int* __restrict__ cnt,
                             int* __restrict__ bsum, int n) {
    __shared__ int lds[256];
    int tid = threadIdx.x;
    int base = blockIdx.x * SCAN_CHUNK + tid * 4;
    int s = 0;
    if (base + 3 < n) {
        int4 v = *(const int4*)(cnt + base);
        s = v.x + v.y + v.z + v.w;
    } else {
        for (int j = 0; j < 4; ++j) if (base + j < n) s += cnt[base + j];
    }
    lds[tid] = s;
    __syncthreads();
    for (int off = 128; off > 0; off >>= 1) {
        if (tid < off) lds[tid] += lds[tid + off];
        __syncthreads();
    }
    if (tid == 0) bsum[blockIdx.x] = lds[0];
}

__global__ void scan_bsum(int* __restrict__ bsum, int nblk,
                          int* __restrict__ start, int n) {
    if (threadIdx.x == 0 && blockIdx.x == 0) {
        int run = 0;
        for (int i = 0; i < nblk; ++i) { int t = bsum[i]; bsum[i] = run; run += t; }
        start[n] = run;   // == E
    }
}

__global__ void scan_final(int* __restrict__ start /* in: cnt, out: start */,
                           int* __restrict__ cur,
                           const int* __restrict__ bsum, int n) {
    __shared__ int lds[256];
    int tid = threadIdx.x;
    int base = blockIdx.x * SCAN_CHUNK + tid * 4;
    int c[4]; int s = 0;
    for (int j = 0; j < 4; ++j) { c[j] = (base + j < n) ? start[base + j] : 0; s += c[j]; }
    lds[tid] = s;
    __syncthreads();
    int v = s;
    for (int off = 1; off < 256; off <<= 1) {
        int t = (tid >= off) ? lds[tid - off] : 0;
        __syncthreads();
        v += t; lds[tid] = v;
        __syncthreads();
    }
    int excl = v - s + bsum[blockIdx.x];
    for (int j = 0; j < 4; ++j) {
        if (base + j < n) { start[base + j] = excl; cur[base + j] = excl; excl += c[j]; }
    }
}

__global__ void fill_kernel(const int* __restrict__ src,
                            const int* __restrict__ dst,
                            const int* __restrict__ rel,
                            int* __restrict__ cur,
                            int* __restrict__ packed, int nE) {
    int e = blockIdx.x * blockDim.x + threadIdx.x;
    if (e >= nE) return;
    int d = dst[e];
    int pos = atomicAdd(cur + d, 1);
    packed[pos] = src[e] | (rel[e] << 24);
}

// ---------------- gather: one wave per dst node, no atomics ----------------
__global__ __launch_bounds__(256) void gather_kernel(
    const unsigned short* __restrict__ hw,
    const int* __restrict__ start,
    const int* __restrict__ packed,
    const float* __restrict__ bias,
    float* __restrict__ outp, float* __restrict__ agg,
    int n, int np, int r0, int rc, int fused)
{
    int wid  = (blockIdx.x * blockDim.x + threadIdx.x) >> 6;
    int lane = threadIdx.x & 63;
    if (wid >= n) return;
    int s = start[wid], e = start[wid + 1];
    float a0 = 0.f, a1 = 0.f;
    for (int base = s; base < e; base += 64) {
        int m = e - base; if (m > 64) m = 64;
        int myp = (base + lane < e) ? packed[base + lane] : 0;
        for (int k = 0; k < m; ++k) {
            int pk = __shfl(myp, k);
            int rr = (int)(((unsigned)pk) >> 24) - r0;
            if ((unsigned)rr >= (unsigned)rc) continue;
            int sn = pk & 0xFFFFFF;
            unsigned int v = *(const unsigned int*)(hw + ((size_t)rr * np + sn) * 128 + lane * 2);
            a0 += bf2f((unsigned short)(v & 0xFFFFu));
            a1 += bf2f((unsigned short)(v >> 16));
        }
    }
    if (fused) {
        float2 b = *(const float2*)(bias + lane * 2);
        float2 o;
        o.x = fmaxf(a0 + b.x, 0.f);
        o.y = fmaxf(a1 + b.y, 0.f);
        *(float2*)(outp + (size_t)wid * 128 + lane * 2) = o;
    } else {
        float* ap = agg + (size_t)wid * 128 + lane * 2;
        ap[0] += a0;
        ap[1] += a1;
    }
}

// ---------------- out = relu(agg + bias)  (fallback path only) ----------------
__global__ void finalize_kernel(const float* __restrict__ agg,
                                const float* __restrict__ bias,
                                float* __restrict__ out, int total4) {
    int t = blockIdx.x * blockDim.x + threadIdx.x;
    if (t >= total4) return;
    float4 a = ((const float4*)agg)[t];
    float4 b = ((const float4*)bias)[t & 31];
    float4 o;
    o.x = fmaxf(a.x + b.x, 0.f);
    o.y = fmaxf(a.y + b.y, 0.f);
    o.z = fmaxf(a.z + b.z, 0.f);
    o.w = fmaxf(a.w + b.w, 0.f);
    ((float4*)out)[t] = o;
}

static inline size_t align256(size_t x) { return (x + 255) & ~(size_t)255; }

extern "C" void kernel_launch(void* const* d_in, const int* in_sizes, int n_in,
                              void* d_out, int out_size, void* d_ws, size_t ws_size,
                              hipStream_t stream) {
    const float* h    = (const float*)d_in[0];
    const float* w    = (const float*)d_in[1];
    const float* bias = (const float*)d_in[2];
    const int*   src  = (const int*)d_in[3];
    const int*   dst  = (const int*)d_in[4];
    const int*   rel  = (const int*)d_in[5];
    float* out = (float*)d_out;

    const int N  = in_sizes[0] / 128;
    const int E  = in_sizes[3];
    const int R  = in_sizes[1] / (128 * 128);
    const int NB = (N + 127) / 128;
    const int NP = NB * 128;
    const int nblk = (N + SCAN_CHUNK - 1) / SCAN_CHUNK;

    char* ws = (char*)d_ws;
    size_t off = 0;
    size_t hbB  = (size_t)NP * 128 * 2;
    unsigned short* hb = (unsigned short*)(ws + off); off = align256(off + hbB);
    size_t wtB  = (size_t)R * 16384 * 2;
    unsigned short* wt = (unsigned short*)(ws + off); off = align256(off + wtB);
    int* startA = (int*)(ws + off); off = align256(off + (size_t)(N + 1) * 4);
    int* curA   = (int*)(ws + off); off = align256(off + (size_t)N * 4);
    int* bsum   = (int*)(ws + off); off = align256(off + (size_t)(nblk > 1024 ? nblk : 1024) * 4);
    int* packed = (int*)(ws + off); off = align256(off + (size_t)E * 4);
    size_t fixed = off;

    size_t perRel = (size_t)NP * 128 * 2;
    size_t aggB   = (size_t)N * 128 * 4;
    size_t avail  = ws_size > fixed ? ws_size - fixed : 0;

    int RC; float* agg; unsigned short* hwb;
    int fused;
    if (avail / perRel >= (size_t)R) {
        RC = R; fused = 1; agg = nullptr;
        hwb = (unsigned short*)(ws + fixed);
    } else {
        fused = 0;
        agg = (float*)(ws + fixed);
        size_t a2 = avail > aggB ? avail - aggB : 0;
        RC = (int)(a2 / perRel);
        if (RC > R) RC = R;
        if (RC < 1) RC = 1;
        hwb = (unsigned short*)(ws + align256(fixed + aggB));
    }

    // init
    hipMemsetAsync(startA, 0, (size_t)(N + 1) * 4, stream);
    if (NP > N)
        hipMemsetAsync(hb + (size_t)N * 128, 0, (size_t)(NP - N) * 128 * 2, stream);
    if (!fused) hipMemsetAsync(agg, 0, aggB, stream);

    int total4 = N * 32;
    cast_h_kernel<<<(total4 + 255) / 256, 256, 0, stream>>>(h, hb, total4);
    wt_kernel<<<R, 256, 0, stream>>>(w, wt);

    // counting sort by dst
    count_kernel<<<(E / 4 + 255) / 256 + 1, 256, 0, stream>>>(dst, startA, E);
    scan_partial<<<nblk, 256, 0, stream>>>(startA, bsum, N);
    scan_bsum<<<1, 64, 0, stream>>>(bsum, nblk, startA, N);
    scan_final<<<nblk, 256, 0, stream>>>(startA, curA, bsum, N);
    fill_kernel<<<(E + 255) / 256, 256, 0, stream>>>(src, dst, rel, curA, packed, E);

    int gblocks = (N * 64 + 255) / 256;
    for (int r0 = 0; r0 < R; r0 += RC) {
        int rc = (R - r0 < RC) ? (R - r0) : RC;
        gemm_kernel<<<dim3(NB, rc), 256, 0, stream>>>(hb, wt, hwb, r0, NP);
        gather_kernel<<<gblocks, 256, 0, stream>>>(hwb, startA, packed, bias,
                                                   out, agg, N, NP, r0, rc, fused);
    }

    if (!fused)
        finalize_kernel<<<(total4 + 255) / 256, 256, 0, stream>>>(agg, bias, out, total4);
}